// Round 4
// baseline (376.145 us; speedup 1.0000x reference)
//
#include <hip/hip_runtime.h>

// BinaryConv2d: out = conv2d(x, sign(w), pad=1) + sign(bias)
// x: [32,256,56,56] f32, w: [256,256,3,3] f32, bias: [256] f32, out: [32,256,56,56] f32
//
// Round 4: A-operand (binary weights) streamed global->VGPR in MFMA-frag order
// (L2-resident 1.18 MB), LDS reserved for the im2col B halo. Barrier-free 9-tap
// inner loop (2 syncs per cc). Next-cc halo prefetched into registers.

#define N_IMG 32
#define C_IN  256
#define H_IN  56
#define W_IN  56
#define O_OUT 256
#define HW    (H_IN * W_IN)      // 3136
#define K_RAW (C_IN * 9)         // 2304 (weight o-stride in raw w)

#define PITCH   40               // bf16 elems per LDS row (80 B: 16B-aligned, 20-bank stride)
#define BS_ROW  (58 * PITCH)     // 2320 elems per halo row
#define XT_HSTR (58 * 32)        // 1856 elems per xt padded row
#define XT_CSTR (58 * 58 * 32)   // 107648 elems per (n,cc) plane

typedef __bf16 bf16x8 __attribute__((ext_vector_type(8)));
typedef float  f32x4  __attribute__((ext_vector_type(4)));

#define XT_ELEMS ((size_t)N_IMG * 8 * 58 * 58 * 32) // 27557888
#define XT_BYTES (XT_ELEMS * 2)                     // 55115776
#define WT2_ELEMS (2 * 8 * 9 * 8 * 64 * 8)          // 589824
#define WT2_BYTES (WT2_ELEMS * 2)                   // 1179648
#define WS_NEED  (XT_BYTES + WT2_BYTES)             // 56295424

// ---- weight binarize + shuffle into A-fragment order ----
// wt2 flat idx = ((((oblk*8 + cc)*9 + tap)*8 + mt)*64 + lane)*8 + j
// element = sign(w[o][c][tap]) with o = oblk*128 + mt*16 + (lane&15),
//           c = cc*32 + (lane>>4)*8 + j   (A[m=lane&15][k=quad*8+j] layout)
__global__ void wshuf_kernel(const float* __restrict__ w, __bf16* __restrict__ wt2) {
    int idx = blockIdx.x * 256 + threadIdx.x;     // 0 .. 73727
    int oc     = idx / 4608;                      // oblk*8 + cc
    int within = idx - oc * 4608;
    int tap    = within >> 9;                     // 0..8
    int r2     = within & 511;
    int mt     = r2 >> 6;                         // 0..7
    int lane   = r2 & 63;
    int oblk   = oc >> 3;
    int cc     = oc & 7;

    int o     = oblk * 128 + mt * 16 + (lane & 15);
    int cbase = cc * 32 + (lane >> 4) * 8;

    bf16x8 v;
#pragma unroll
    for (int j = 0; j < 8; ++j) {
        float f = w[(size_t)o * K_RAW + (size_t)(cbase + j) * 9 + tap];
        v[j] = (f >= 0.0f) ? (__bf16)1.0f : (__bf16)(-1.0f);
    }
    *(bf16x8*)(wt2 + (size_t)idx * 8) = v;
}

// ---- x transpose: NCHW f32 -> [n][cc][hh][ww][c32] bf16, zero-padded border ----
__global__ void xtrans_kernel(const float* __restrict__ x, __bf16* __restrict__ xt) {
    const int hh = blockIdx.x;         // 0..57
    const int cc = blockIdx.y;         // 0..7
    const int n  = blockIdx.z;         // 0..31
    const int t  = threadIdx.x;
    const int ww = t >> 2;             // 0..63 (valid < 58)
    const int cy = t & 3;              // 8 channels each
    if (ww >= 58) return;

    bf16x8 v = (bf16x8){0, 0, 0, 0, 0, 0, 0, 0};
    if (hh >= 1 && hh <= 56 && ww >= 1 && ww <= 56) {
        const float* src = x + ((size_t)n * C_IN + cc * 32 + cy * 8) * HW
                             + (hh - 1) * W_IN + (ww - 1);
#pragma unroll
        for (int j = 0; j < 8; ++j)
            v[j] = (__bf16)src[(size_t)j * HW];
    }
    __bf16* dst = xt + (((size_t)(n * 8 + cc) * 58 + hh) * 58 + ww) * 32 + cy * 8;
    *(bf16x8*)dst = v;
}

// ---- main: block = 128 o x 224 px (4 out rows x 56), A from global, B from LDS ----
__launch_bounds__(256, 2)
__global__ void bconv3_kernel(const __bf16* __restrict__ xt,
                              const __bf16* __restrict__ wt2,
                              const float* __restrict__ bias,
                              float* __restrict__ out) {
    __shared__ __attribute__((aligned(16))) __bf16 Bs[6 * BS_ROW];   // 27840 B halo

    const int tid  = threadIdx.x;
    const int lane = tid & 63;
    const int wv   = tid >> 6;
    const int row  = lane & 15;
    const int quad = lane >> 4;

    const int nrp  = blockIdx.x;              // 0..447
    const int n    = nrp / 14;
    const int rp   = nrp - n * 14;
    const int oblk = blockIdx.y;              // 0..1
    const int h0   = rp * 4;                  // first output row of tile

    // per-lane output pixel coords (nt = 0..3), p in [0,256), live if p < 224
    int pr[4], pc[4];
    bool live[4];
#pragma unroll
    for (int nt = 0; nt < 4; ++nt) {
        int p = wv * 64 + nt * 16 + row;
        live[nt] = (p < 224);
        int r = p / 56;
        int c = p - r * 56;
        if (!live[nt]) { r = 0; c = 0; }
        pr[nt] = r;
        pc[nt] = c;
    }

    f32x4 acc[8][4];
#pragma unroll
    for (int mt = 0; mt < 8; ++mt)
#pragma unroll
        for (int nt = 0; nt < 4; ++nt)
            acc[mt][nt] = (f32x4){0.f, 0.f, 0.f, 0.f};

    // ---- halo prefetch registers (tid < 232 participates) ----
    const int hcol = tid >> 2;       // 0..57 (when tid<232)
    const int hcg  = tid & 3;        // 0..3
    bf16x8 hreg[6];

    auto loadHalo = [&](int cc) {
        if (tid < 232) {
            const __bf16* bbase = xt + (size_t)(n * 8 + cc) * XT_CSTR + (size_t)h0 * XT_HSTR;
#pragma unroll
            for (int r6 = 0; r6 < 6; ++r6)
                hreg[r6] = *(const bf16x8*)(bbase + r6 * XT_HSTR + tid * 8);
        }
    };

    loadHalo(0);

    for (int cc = 0; cc < 8; ++cc) {
        __syncthreads();   // previous cc's Bs readers done
        if (tid < 232) {
#pragma unroll
            for (int r6 = 0; r6 < 6; ++r6)
                *(bf16x8*)(&Bs[r6 * BS_ROW + hcol * PITCH + hcg * 8]) = hreg[r6];
        }
        __syncthreads();   // Bs visible
        if (cc < 7) loadHalo(cc + 1);   // overlaps the 9-tap compute below

        // A-stream base for this (oblk, cc): step stride 4096 elems
        const __bf16* abase0 = wt2 + (size_t)((oblk * 8 + cc) * 9) * 4096 + lane * 8;

        for (int tap = 0; tap < 9; ++tap) {
            const int dh = tap / 3;
            const int dw = tap - dh * 3;
            const __bf16* awave = abase0 + (size_t)tap * 4096;

            bf16x8 bfrag[4];
#pragma unroll
            for (int nt = 0; nt < 4; ++nt)
                bfrag[nt] = *(const bf16x8*)(
                    &Bs[(pr[nt] + dh) * BS_ROW + (pc[nt] + dw) * PITCH + quad * 8]);

            bf16x8 af[8];
#pragma unroll
            for (int mt = 0; mt < 8; ++mt)
                af[mt] = *(const bf16x8*)(awave + mt * 512);

#pragma unroll
            for (int mt = 0; mt < 8; ++mt)
#pragma unroll
                for (int nt = 0; nt < 4; ++nt)
                    acc[mt][nt] = __builtin_amdgcn_mfma_f32_16x16x32_bf16(
                        af[mt], bfrag[nt], acc[mt][nt], 0, 0, 0);
        }
    }

    // ---- epilogue: o = oblk*128 + mt*16 + quad*4 + r; pix = (h0+pr, pc) ----
#pragma unroll
    for (int nt = 0; nt < 4; ++nt) {
        if (!live[nt]) continue;
        float* obase = out + ((size_t)n * O_OUT + oblk * 128) * HW
                           + (h0 + pr[nt]) * W_IN + pc[nt];
#pragma unroll
        for (int mt = 0; mt < 8; ++mt) {
#pragma unroll
            for (int r = 0; r < 4; ++r) {
                int ol = mt * 16 + quad * 4 + r;
                float sb = (bias[oblk * 128 + ol] >= 0.0f) ? 1.0f : -1.0f;
                obase[(size_t)ol * HW] = acc[mt][nt][r] + sb;
            }
        }
    }
}

// ================= minimal fallback (only if ws too small) =================
#define CHW (C_IN * HW)

__launch_bounds__(256, 2)
__global__ void bconv_fallback(const float* __restrict__ x,
                               const float* __restrict__ w,
                               const float* __restrict__ bias,
                               float* __restrict__ out) {
    __shared__ __attribute__((aligned(16))) __bf16 Asf[128 * PITCH];
    __shared__ __attribute__((aligned(16))) __bf16 Bsf[128 * PITCH];

    const int tid  = threadIdx.x;
    const int lane = tid & 63;
    const int wv   = tid >> 6;
    const int pblk = blockIdx.x;
    const int oblk = blockIdx.y;

    const int p_local = tid & 127;
    const int cgrp    = tid >> 7;
    const int pixel   = pblk * 128 + p_local;
    const int n_img   = pixel / HW;
    const int hw      = pixel - n_img * HW;
    const int h       = hw / W_IN;
    const int wx      = hw - h * W_IN;
    const float* xbase = x + (size_t)n_img * CHW;

    f32x4 acc[8][2];
#pragma unroll
    for (int mt = 0; mt < 8; ++mt)
#pragma unroll
        for (int nt = 0; nt < 2; ++nt)
            acc[mt][nt] = (f32x4){0.f, 0.f, 0.f, 0.f};

    const int pix_wave = wv * 32;
    const int row  = lane & 15;
    const int quad = lane >> 4;

    for (int tap = 0; tap < 9; ++tap) {
        const int dh = tap / 3 - 1;
        const int dw = tap % 3 - 1;
        const int hh = h + dh;
        const int ww = wx + dw;
        const bool valid = ((unsigned)hh < (unsigned)H_IN) && ((unsigned)ww < (unsigned)W_IN);
        const int offs = hh * W_IN + ww;

        for (int ck = 0; ck < 8; ++ck) {
            __syncthreads();
#pragma unroll
            for (int rep = 0; rep < 2; ++rep) {
                int v  = tid + rep * 256;
                int oa = v >> 2;
                int c8 = v & 3;
                const float* wsrc = w + (size_t)(oblk * 128 + oa) * K_RAW
                                      + (ck * 32 + c8 * 8) * 9 + tap;
                bf16x8 val;
#pragma unroll
                for (int j = 0; j < 8; ++j)
                    val[j] = (wsrc[j * 9] >= 0.0f) ? (__bf16)1.0f : (__bf16)(-1.0f);
                *(bf16x8*)(&Asf[oa * PITCH + c8 * 8]) = val;
            }
            {
                const int cbase = (ck * 32 + cgrp * 16) * HW + offs;
#pragma unroll
                for (int g = 0; g < 2; ++g) {
                    bf16x8 vb;
#pragma unroll
                    for (int j = 0; j < 8; ++j) {
                        float f = valid ? xbase[cbase + (g * 8 + j) * HW] : 0.0f;
                        vb[j] = (__bf16)f;
                    }
                    *(bf16x8*)(&Bsf[p_local * PITCH + cgrp * 16 + g * 8]) = vb;
                }
            }
            __syncthreads();
            bf16x8 bfrag[2];
#pragma unroll
            for (int nt = 0; nt < 2; ++nt)
                bfrag[nt] = *(const bf16x8*)(&Bsf[(pix_wave + nt * 16 + row) * PITCH + quad * 8]);
#pragma unroll
            for (int mt = 0; mt < 8; ++mt) {
                bf16x8 afrag = *(const bf16x8*)(&Asf[(mt * 16 + row) * PITCH + quad * 8]);
#pragma unroll
                for (int nt = 0; nt < 2; ++nt)
                    acc[mt][nt] = __builtin_amdgcn_mfma_f32_16x16x32_bf16(
                        afrag, bfrag[nt], acc[mt][nt], 0, 0, 0);
            }
        }
    }

#pragma unroll
    for (int nt = 0; nt < 2; ++nt) {
        int pix = pblk * 128 + pix_wave + nt * 16 + row;
        int ni  = pix / HW;
        int phw = pix - ni * HW;
        float* obase = out + (size_t)ni * (O_OUT * HW) + phw;
#pragma unroll
        for (int mt = 0; mt < 8; ++mt) {
            int o0 = oblk * 128 + mt * 16 + quad * 4;
#pragma unroll
            for (int r = 0; r < 4; ++r) {
                int o = o0 + r;
                float sb = (bias[o] >= 0.0f) ? 1.0f : -1.0f;
                obase[(size_t)o * HW] = acc[mt][nt][r] + sb;
            }
        }
    }
}

extern "C" void kernel_launch(void* const* d_in, const int* in_sizes, int n_in,
                              void* d_out, int out_size, void* d_ws, size_t ws_size,
                              hipStream_t stream) {
    const float* x    = (const float*)d_in[0];
    const float* w    = (const float*)d_in[1];
    const float* bias = (const float*)d_in[2];
    float* out        = (float*)d_out;

    if (ws_size >= (size_t)WS_NEED) {
        __bf16* xt  = (__bf16*)d_ws;
        __bf16* wt2 = (__bf16*)((char*)d_ws + XT_BYTES);
        xtrans_kernel<<<dim3(58, 8, N_IMG), dim3(256), 0, stream>>>(x, xt);
        wshuf_kernel<<<(2 * 8 * 9 * 8 * 64) / 256, 256, 0, stream>>>(w, wt2);
        bconv3_kernel<<<dim3(N_IMG * 14, 2), dim3(256), 0, stream>>>(xt, wt2, bias, out);
    } else {
        bconv_fallback<<<dim3((N_IMG * HW) / 128, 2), dim3(256), 0, stream>>>(
            x, w, bias, out);
    }
}

// Round 5
// 321.321 us; speedup vs baseline: 1.1706x; 1.1706x over previous
//
#include <hip/hip_runtime.h>
#include <stdint.h>

// BinaryConv2d: out = conv2d(x, sign(w), pad=1) + sign(bias)
// x: [32,256,56,56] f32, w: [256,256,3,3] f32, bias: [256] f32, out: [32,256,56,56] f32
//
// Round 5: int8 implicit GEMM. Weights are exactly +-1 in i8; x is quantized with a
// dynamic global scale (127/absmax). mfma_i32_16x16x64_i8 packs K=64 into the same
// 16 B/lane fragment bf16 uses for K=32: half the LDS bytes per FLOP, 2x MFMA rate.
// i32 accumulation is exact; out = acc * absmax/127 + sign(bias).

#define N_IMG 32
#define C_IN  256
#define H_IN  56
#define W_IN  56
#define O_OUT 256
#define HW    (H_IN * W_IN)      // 3136
#define K_RAW (C_IN * 9)         // 2304

typedef int8_t i8x16 __attribute__((ext_vector_type(16)));
typedef int    i32x4 __attribute__((ext_vector_type(4)));
typedef float  f32x4 __attribute__((ext_vector_type(4)));
typedef __bf16 bf16x8 __attribute__((ext_vector_type(8)));   // fallback only

// xq layout: [n][cc4][hh58][ww58][c64] i8 (zero border)
#define XQ_WSTR (58 * 64)        // 3712 B per padded row
#define XQ_CSTR (58 * 58 * 64)   // 215296 B per (n,cc) plane
#define XQ_BYTES ((size_t)N_IMG * 4 * XQ_CSTR)       // 27,557,888
// wq layout: [(cc*9+tap)][o256][c64] i8
#define WQ_BYTES ((size_t)36 * 256 * 64)             // 589,824
#define AM_OFF   (XQ_BYTES + WQ_BYTES)
#define WS_NEED  (AM_OFF + 64)

#define BPITCH  80               // LDS bytes per pixel row (64 data + 16 pad)
#define BS_ROWB (58 * BPITCH)    // 4640 B per halo row
#define APITCH  80

// ---- absmax(x) reduction ----
__global__ void amax_zero(unsigned* am) {
    if (threadIdx.x == 0 && blockIdx.x == 0) *am = 0u;
}

__global__ void amax_kernel(const float* __restrict__ x, unsigned* __restrict__ am) {
    const size_t NV = (size_t)N_IMG * C_IN * HW / 4;   // 6,422,528 float4
    float m = 0.f;
    for (size_t i = (size_t)blockIdx.x * 256 + threadIdx.x; i < NV;
         i += (size_t)gridDim.x * 256) {
        f32x4 v = ((const f32x4*)x)[i];
        m = fmaxf(m, fmaxf(fmaxf(fabsf(v[0]), fabsf(v[1])),
                           fmaxf(fabsf(v[2]), fabsf(v[3]))));
    }
#pragma unroll
    for (int off = 32; off; off >>= 1)
        m = fmaxf(m, __shfl_down(m, off));
    __shared__ float red[4];
    if ((threadIdx.x & 63) == 0) red[threadIdx.x >> 6] = m;
    __syncthreads();
    if (threadIdx.x == 0) {
        m = fmaxf(fmaxf(red[0], red[1]), fmaxf(red[2], red[3]));
        atomicMax(am, __float_as_uint(m));   // abs values: uint order == float order
    }
}

// ---- x quantize + transpose: NCHW f32 -> [n][cc4][hh][ww][c64] i8, zero border ----
__global__ void xtrans_q(const float* __restrict__ x, int8_t* __restrict__ xq,
                         const unsigned* __restrict__ amax_bits) {
    const int hh = blockIdx.x;   // 0..57
    const int cc = blockIdx.y;   // 0..3
    const int n  = blockIdx.z;   // 0..31
    const int t  = threadIdx.x;
    const int ww = t >> 2;       // 0..63 (valid < 58)
    const int cy = t & 3;        // 16 channels each
    if (ww >= 58) return;

    const float am    = __uint_as_float(*amax_bits);
    const float scale = 127.f / fmaxf(am, 1e-20f);

    i8x16 v;
    if (hh >= 1 && hh <= 56 && ww >= 1 && ww <= 56) {
        const float* src = x + ((size_t)n * C_IN + cc * 64 + cy * 16) * HW
                             + (hh - 1) * W_IN + (ww - 1);
#pragma unroll
        for (int j = 0; j < 16; ++j) {
            float f = src[(size_t)j * HW] * scale;
            f = fminf(fmaxf(f, -127.f), 127.f);
            v[j] = (int8_t)(int)rintf(f);
        }
    } else {
#pragma unroll
        for (int j = 0; j < 16; ++j) v[j] = 0;
    }
    *(i8x16*)(xq + ((size_t)(n * 4 + cc) * 3364 + hh * 58 + ww) * 64 + cy * 16) = v;
}

// ---- weight binarize: wq[(cc*9+tap)][o][c64] = sign(w[o][cc*64+c][tap]) in i8 ----
__global__ void wshuf_q(const float* __restrict__ w, int8_t* __restrict__ wq) {
    int idx = blockIdx.x * 256 + threadIdx.x;   // 0..36863 chunks of 16 B
    int cg  = idx & 3;
    int o   = (idx >> 2) & 255;
    int st  = idx >> 10;            // 0..35 = cc*9 + tap
    int tap = st % 9;
    int cc  = st / 9;
    i8x16 v;
#pragma unroll
    for (int j = 0; j < 16; ++j) {
        int ch = cc * 64 + cg * 16 + j;
        float f = w[(size_t)o * K_RAW + ch * 9 + tap];
        v[j] = (f >= 0.0f) ? (int8_t)1 : (int8_t)-1;
    }
    *(i8x16*)(wq + (size_t)idx * 16) = v;
}

// ---- main: block = 128 o x 224 px (4 out rows x 56), 4 cc-chunks of K=64 x 9 taps ----
__launch_bounds__(256, 2)
__global__ void bconv_i8(const int8_t* __restrict__ xq,
                         const int8_t* __restrict__ wq,
                         const float* __restrict__ bias,
                         const unsigned* __restrict__ amax_bits,
                         float* __restrict__ out) {
    __shared__ __attribute__((aligned(16))) int8_t Bs[6 * BS_ROWB];      // 27840 B
    __shared__ __attribute__((aligned(16))) int8_t As[2][128 * APITCH];  // 2 x 10240 B

    const int tid  = threadIdx.x;
    const int lane = tid & 63;
    const int wv   = tid >> 6;
    const int row  = lane & 15;
    const int quad = lane >> 4;

    const int nrp  = blockIdx.x;              // 0..447
    const int n    = nrp / 14;
    const int rp   = nrp - n * 14;
    const int oblk = blockIdx.y;              // 0..1
    const int h0   = rp * 4;

    int pr[4], pc[4];
    bool live[4];
#pragma unroll
    for (int nt = 0; nt < 4; ++nt) {
        int p = wv * 64 + nt * 16 + row;
        live[nt] = (p < 224);
        int r = p / 56;
        int c = p - r * 56;
        if (!live[nt]) { r = 0; c = 0; }
        pr[nt] = r;
        pc[nt] = c;
    }

    i32x4 acc[8][4];
#pragma unroll
    for (int mt = 0; mt < 8; ++mt)
#pragma unroll
        for (int nt = 0; nt < 4; ++nt)
            acc[mt][nt] = (i32x4){0, 0, 0, 0};

    // halo register prefetch (tid < 232)
    i32x4 hreg[6];
    auto loadHalo = [&](int cc) {
        if (tid < 232) {
            const int8_t* bbase = xq + (size_t)(n * 4 + cc) * XQ_CSTR + (size_t)h0 * XQ_WSTR;
#pragma unroll
            for (int r6 = 0; r6 < 6; ++r6)
                hreg[r6] = *(const i32x4*)(bbase + r6 * XQ_WSTR + tid * 16);
        }
    };

    // stage A-tile for step s = cc*9 + tap into buffer buf (128 o x 64 i8)
    auto stageA = [&](int s, int buf) {
        const int8_t* asrc = wq + (size_t)s * 16384 + oblk * 8192;
#pragma unroll
        for (int it = 0; it < 2; ++it) {
            int idx = tid + it * 256;
            int o   = idx >> 2;
            int cg  = idx & 3;
            *(i32x4*)(&As[buf][o * APITCH + cg * 16]) =
                *(const i32x4*)(asrc + o * 64 + cg * 16);
        }
    };

    stageA(0, 0);
    loadHalo(0);

    for (int cc = 0; cc < 4; ++cc) {
        __syncthreads();   // prior cc's Bs readers done
        if (tid < 232) {
            const int col = tid >> 2;
            const int cg  = tid & 3;
#pragma unroll
            for (int r6 = 0; r6 < 6; ++r6)
                *(i32x4*)(&Bs[r6 * BS_ROWB + col * BPITCH + cg * 16]) = hreg[r6];
        }
        if (cc < 3) loadHalo(cc + 1);   // overlaps the 9-tap compute

        for (int tap = 0; tap < 9; ++tap) {
            const int s = cc * 9 + tap;
            __syncthreads();   // Bs visible (tap0); As[s&1] staged last step visible
            if (s + 1 < 36) stageA(s + 1, (s + 1) & 1);

            const int dh = tap / 3;
            const int dw = tap - dh * 3;
            const int8_t* Ab = As[s & 1];

            i32x4 bfrag[4];
#pragma unroll
            for (int nt = 0; nt < 4; ++nt)
                bfrag[nt] = *(const i32x4*)(
                    &Bs[(pr[nt] + dh) * BS_ROWB + (pc[nt] + dw) * BPITCH + quad * 16]);
#pragma unroll
            for (int mt = 0; mt < 8; ++mt) {
                i32x4 af = *(const i32x4*)(&Ab[(mt * 16 + row) * APITCH + quad * 16]);
#pragma unroll
                for (int nt = 0; nt < 4; ++nt)
                    acc[mt][nt] = __builtin_amdgcn_mfma_i32_16x16x64_i8(
                        af, bfrag[nt], acc[mt][nt], 0, 0, 0);
            }
        }
    }

    // epilogue: o = oblk*128 + mt*16 + quad*4 + r; pix = (h0+pr, pc)
    const float am  = __uint_as_float(*amax_bits);
    const float inv = am * (1.0f / 127.0f);
#pragma unroll
    for (int nt = 0; nt < 4; ++nt) {
        if (!live[nt]) continue;
        float* obase = out + ((size_t)n * O_OUT + oblk * 128) * HW
                           + (h0 + pr[nt]) * W_IN + pc[nt];
#pragma unroll
        for (int mt = 0; mt < 8; ++mt) {
#pragma unroll
            for (int r = 0; r < 4; ++r) {
                int ol = mt * 16 + quad * 4 + r;
                float sb = (bias[oblk * 128 + ol] >= 0.0f) ? 1.0f : -1.0f;
                obase[(size_t)ol * HW] = (float)acc[mt][nt][r] * inv + sb;
            }
        }
    }
}

// ================= fallback (only if ws too small): fp32->bf16 direct =================
#define CHW (C_IN * HW)
#define FPITCH 40

__launch_bounds__(256, 2)
__global__ void bconv_fallback(const float* __restrict__ x,
                               const float* __restrict__ w,
                               const float* __restrict__ bias,
                               float* __restrict__ out) {
    __shared__ __attribute__((aligned(16))) __bf16 Asf[128 * FPITCH];
    __shared__ __attribute__((aligned(16))) __bf16 Bsf[128 * FPITCH];

    const int tid  = threadIdx.x;
    const int lane = tid & 63;
    const int wv   = tid >> 6;
    const int pblk = blockIdx.x;
    const int oblk = blockIdx.y;

    const int p_local = tid & 127;
    const int cgrp    = tid >> 7;
    const int pixel   = pblk * 128 + p_local;
    const int n_img   = pixel / HW;
    const int hw      = pixel - n_img * HW;
    const int h       = hw / W_IN;
    const int wx      = hw - h * W_IN;
    const float* xbase = x + (size_t)n_img * CHW;

    f32x4 acc[8][2];
#pragma unroll
    for (int mt = 0; mt < 8; ++mt)
#pragma unroll
        for (int nt = 0; nt < 2; ++nt)
            acc[mt][nt] = (f32x4){0.f, 0.f, 0.f, 0.f};

    const int pix_wave = wv * 32;
    const int row  = lane & 15;
    const int quad = lane >> 4;

    for (int tap = 0; tap < 9; ++tap) {
        const int dh = tap / 3 - 1;
        const int dw = tap % 3 - 1;
        const int hh = h + dh;
        const int ww = wx + dw;
        const bool valid = ((unsigned)hh < (unsigned)H_IN) && ((unsigned)ww < (unsigned)W_IN);
        const int offs = hh * W_IN + ww;

        for (int ck = 0; ck < 8; ++ck) {
            __syncthreads();
#pragma unroll
            for (int rep = 0; rep < 2; ++rep) {
                int v  = tid + rep * 256;
                int oa = v >> 2;
                int c8 = v & 3;
                const float* wsrc = w + (size_t)(oblk * 128 + oa) * K_RAW
                                      + (ck * 32 + c8 * 8) * 9 + tap;
                bf16x8 val;
#pragma unroll
                for (int j = 0; j < 8; ++j)
                    val[j] = (wsrc[j * 9] >= 0.0f) ? (__bf16)1.0f : (__bf16)(-1.0f);
                *(bf16x8*)(&Asf[oa * FPITCH + c8 * 8]) = val;
            }
            {
                const int cbase = (ck * 32 + cgrp * 16) * HW + offs;
#pragma unroll
                for (int g = 0; g < 2; ++g) {
                    bf16x8 vb;
#pragma unroll
                    for (int j = 0; j < 8; ++j) {
                        float f = valid ? xbase[cbase + (g * 8 + j) * HW] : 0.0f;
                        vb[j] = (__bf16)f;
                    }
                    *(bf16x8*)(&Bsf[p_local * FPITCH + cgrp * 16 + g * 8]) = vb;
                }
            }
            __syncthreads();
            bf16x8 bfrag[2];
#pragma unroll
            for (int nt = 0; nt < 2; ++nt)
                bfrag[nt] = *(const bf16x8*)(&Bsf[(pix_wave + nt * 16 + row) * FPITCH + quad * 8]);
#pragma unroll
            for (int mt = 0; mt < 8; ++mt) {
                bf16x8 afrag = *(const bf16x8*)(&Asf[(mt * 16 + row) * FPITCH + quad * 8]);
#pragma unroll
                for (int nt = 0; nt < 2; ++nt)
                    acc[mt][nt] = __builtin_amdgcn_mfma_f32_16x16x32_bf16(
                        afrag, bfrag[nt], acc[mt][nt], 0, 0, 0);
            }
        }
    }

#pragma unroll
    for (int nt = 0; nt < 2; ++nt) {
        int pix = pblk * 128 + pix_wave + nt * 16 + row;
        int ni  = pix / HW;
        int phw = pix - ni * HW;
        float* obase = out + (size_t)ni * (O_OUT * HW) + phw;
#pragma unroll
        for (int mt = 0; mt < 8; ++mt) {
            int o0 = oblk * 128 + mt * 16 + quad * 4;
#pragma unroll
            for (int r = 0; r < 4; ++r) {
                int o = o0 + r;
                float sb = (bias[o] >= 0.0f) ? 1.0f : -1.0f;
                obase[(size_t)o * HW] = acc[mt][nt][r] + sb;
            }
        }
    }
}

extern "C" void kernel_launch(void* const* d_in, const int* in_sizes, int n_in,
                              void* d_out, int out_size, void* d_ws, size_t ws_size,
                              hipStream_t stream) {
    const float* x    = (const float*)d_in[0];
    const float* w    = (const float*)d_in[1];
    const float* bias = (const float*)d_in[2];
    float* out        = (float*)d_out;

    if (ws_size >= WS_NEED) {
        int8_t*   xq = (int8_t*)d_ws;
        int8_t*   wq = (int8_t*)d_ws + XQ_BYTES;
        unsigned* am = (unsigned*)((char*)d_ws + AM_OFF);

        amax_zero<<<1, 64, 0, stream>>>(am);
        amax_kernel<<<1024, 256, 0, stream>>>(x, am);
        xtrans_q<<<dim3(58, 4, N_IMG), dim3(256), 0, stream>>>(x, xq, am);
        wshuf_q<<<144, 256, 0, stream>>>(w, (int8_t*)wq);
        bconv_i8<<<dim3(N_IMG * 14, 2), dim3(256), 0, stream>>>(xq, wq, bias, am, out);
    } else {
        bconv_fallback<<<dim3((N_IMG * HW) / 128, 2), dim3(256), 0, stream>>>(
            x, w, bias, out);
    }
}

// Round 6
// 300.132 us; speedup vs baseline: 1.2533x; 1.0706x over previous
//
#include <hip/hip_runtime.h>
#include <stdint.h>

// BinaryConv2d: out = conv2d(x, sign(w), pad=1) + sign(bias)
// x: [32,256,56,56] f32, w: [256,256,3,3] f32, bias: [256] f32, out: [32,256,56,56] f32
//
// Round 6: int8 implicit GEMM with software-pipelined K-loop:
//  - A (binary weights) staged via global_load_lds (DMA, width 16), double-buffered,
//    issued 1-2 taps ahead; k-chunk permutation baked into wq so the pitch-64 LDS
//    A-reads are bank-conflict-free.
//  - B halo staged per cc (stable across 9 taps); B-fragments for tap+1 and
//    A-fragments for tap+1 prefetched into registers under the tap-t MFMA block.

#define N_IMG 32
#define C_IN  256
#define H_IN  56
#define W_IN  56
#define O_OUT 256
#define HW    (H_IN * W_IN)      // 3136
#define K_RAW (C_IN * 9)         // 2304

typedef int8_t i8x16 __attribute__((ext_vector_type(16)));
typedef int    i32x4 __attribute__((ext_vector_type(4)));
typedef float  f32x4 __attribute__((ext_vector_type(4)));
typedef __bf16 bf16x8 __attribute__((ext_vector_type(8)));   // fallback only

// xq layout: [n][cc4][hh58][ww58][c64] i8 (zero border)
#define XQ_WSTR (58 * 64)        // 3712 B per padded row
#define XQ_CSTR (58 * 58 * 64)   // 215296 B per (n,cc) plane
#define XQ_BYTES ((size_t)N_IMG * 4 * XQ_CSTR)       // 27,557,888
// wq layout: [s=cc*9+tap][o256][c64] i8, k-chunk permuted (see wshuf_q)
#define WQ_BYTES ((size_t)36 * 256 * 64)             // 589,824
#define AM_OFF   (XQ_BYTES + WQ_BYTES)
#define WS_NEED  (AM_OFF + 64)

#define BPITCH  80               // LDS bytes per pixel row (64 data + 16 pad) — conflict-free
#define BS_ROWB (58 * BPITCH)    // 4640 B per halo row

#define AS1 __attribute__((address_space(1)))
#define AS3 __attribute__((address_space(3)))

__device__ __forceinline__ void dma16(const void* g, void* l) {
    __builtin_amdgcn_global_load_lds((const AS1 uint32_t*)g, (AS3 uint32_t*)l, 16, 0, 0);
}

// ---- absmax(x) reduction ----
__global__ void amax_zero(unsigned* am) {
    if (threadIdx.x == 0 && blockIdx.x == 0) *am = 0u;
}

__global__ void amax_kernel(const float* __restrict__ x, unsigned* __restrict__ am) {
    const size_t NV = (size_t)N_IMG * C_IN * HW / 4;   // float4 count
    float m = 0.f;
    for (size_t i = (size_t)blockIdx.x * 256 + threadIdx.x; i < NV;
         i += (size_t)gridDim.x * 256) {
        f32x4 v = ((const f32x4*)x)[i];
        m = fmaxf(m, fmaxf(fmaxf(fabsf(v[0]), fabsf(v[1])),
                           fmaxf(fabsf(v[2]), fabsf(v[3]))));
    }
#pragma unroll
    for (int off = 32; off; off >>= 1)
        m = fmaxf(m, __shfl_down(m, off));
    __shared__ float red[4];
    if ((threadIdx.x & 63) == 0) red[threadIdx.x >> 6] = m;
    __syncthreads();
    if (threadIdx.x == 0) {
        m = fmaxf(fmaxf(red[0], red[1]), fmaxf(red[2], red[3]));
        atomicMax(am, __float_as_uint(m));   // abs floats: uint order == float order
    }
}

// ---- x quantize + transpose: NCHW f32 -> [n][cc4][hh][ww][c64] i8, zero border ----
__global__ void xtrans_q(const float* __restrict__ x, int8_t* __restrict__ xq,
                         const unsigned* __restrict__ amax_bits) {
    const int hh = blockIdx.x;   // 0..57
    const int cc = blockIdx.y;   // 0..3
    const int n  = blockIdx.z;   // 0..31
    const int t  = threadIdx.x;
    const int ww = t >> 2;       // 0..63 (valid < 58)
    const int cy = t & 3;        // 16 channels each
    if (ww >= 58) return;

    const float am    = __uint_as_float(*amax_bits);
    const float scale = 127.f / fmaxf(am, 1e-20f);

    i8x16 v;
    if (hh >= 1 && hh <= 56 && ww >= 1 && ww <= 56) {
        const float* src = x + ((size_t)n * C_IN + cc * 64 + cy * 16) * HW
                             + (hh - 1) * W_IN + (ww - 1);
#pragma unroll
        for (int j = 0; j < 16; ++j) {
            float f = src[(size_t)j * HW] * scale;
            f = fminf(fmaxf(f, -127.f), 127.f);
            v[j] = (int8_t)(int)rintf(f);
        }
    } else {
#pragma unroll
        for (int j = 0; j < 16; ++j) v[j] = 0;
    }
    *(i8x16*)(xq + ((size_t)(n * 4 + cc) * 3364 + hh * 58 + ww) * 64 + cy * 16) = v;
}

// ---- weight binarize with k-chunk permutation ----
// Position (s, o, cpos) stores TRUE k-chunk (cpos - ((o&15)>>1)) & 3, so a reader
// at chunk position (quad + (row>>1)) & 3 (row = o&15) recovers chunk `quad`
// while making pitch-64 LDS reads exactly 2-way (free) on the 32 banks.
__global__ void wshuf_q(const float* __restrict__ w, int8_t* __restrict__ wq) {
    int idx  = blockIdx.x * 256 + threadIdx.x;   // 0..36863 chunks of 16 B
    int cpos = idx & 3;
    int o    = (idx >> 2) & 255;
    int st   = idx >> 10;            // 0..35 = cc*9 + tap
    int tap  = st % 9;
    int cc   = st / 9;
    int truec = (cpos - ((o & 15) >> 1)) & 3;
    i8x16 v;
#pragma unroll
    for (int j = 0; j < 16; ++j) {
        int ch = cc * 64 + truec * 16 + j;
        float f = w[(size_t)o * K_RAW + ch * 9 + tap];
        v[j] = (f >= 0.0f) ? (int8_t)1 : (int8_t)-1;
    }
    *(i8x16*)(wq + (size_t)idx * 16) = v;
}

// ---- main: block = 128 o x 224 px (4 out rows x 56), pipelined K-loop ----
__launch_bounds__(256, 2)
__global__ void bconv_i8(const int8_t* __restrict__ xq,
                         const int8_t* __restrict__ wq,
                         const float* __restrict__ bias,
                         const unsigned* __restrict__ amax_bits,
                         float* __restrict__ out) {
    __shared__ __attribute__((aligned(16))) int8_t As[2 * 8192];     // A dbuf (DMA dest)
    __shared__ __attribute__((aligned(16))) int8_t Bs[6 * BS_ROWB];  // 27840 B halo

    const int tid  = threadIdx.x;
    const int lane = tid & 63;
    const int wv   = tid >> 6;
    const int row  = lane & 15;
    const int quad = lane >> 4;

    const int nrp  = blockIdx.x;              // 0..447
    const int n    = nrp / 14;
    const int rp   = nrp - n * 14;
    const int oblk = blockIdx.y;              // 0..1
    const int h0   = rp * 4;

    int pr[4], pc[4];
    bool live[4];
#pragma unroll
    for (int nt = 0; nt < 4; ++nt) {
        int p = wv * 64 + nt * 16 + row;
        live[nt] = (p < 224);
        int r = p / 56;
        int c = p - r * 56;
        if (!live[nt]) { r = 0; c = 0; }
        pr[nt] = r;
        pc[nt] = c;
    }

    i32x4 acc[8][4];
#pragma unroll
    for (int mt = 0; mt < 8; ++mt)
#pragma unroll
        for (int nt = 0; nt < 4; ++nt)
            acc[mt][nt] = (i32x4){0, 0, 0, 0};

    // A-read lane address: permuted chunk -> conflict-free at pitch 64
    const int rowA = row * 64 + (((quad + (row >> 1)) & 3) << 4);
    // B-read lane base addresses (tap offsets become static immediates)
    int addrB[4];
#pragma unroll
    for (int nt = 0; nt < 4; ++nt)
        addrB[nt] = pr[nt] * BS_ROWB + pc[nt] * BPITCH + quad * 16;

    // DMA A-tile for step s into As[s&1] (each wave stages its 2 KB quarter)
    auto issueA = [&](int s) {
        const int8_t* g = wq + (size_t)s * 16384 + oblk * 8192 + wv * 2048 + lane * 16;
        int8_t* l = &As[(s & 1) * 8192 + wv * 2048];
        dma16(g, l);
        dma16(g + 1024, l + 1024);
    };

    issueA(0);   // prologue

    i32x4 af[8], bc[4], bn[4];

    for (int cc = 0; cc < 4; ++cc) {
        const int s0 = cc * 9;
        __syncthreads();   // all readers of prev-cc Bs / As done
        // ---- stage B halo for this cc: 6 rows x 58 cols x 64 ch, direct glb->LDS ----
        if (tid < 232) {
            const int8_t* bbase = xq + (size_t)(n * 4 + cc) * XQ_CSTR
                                     + (size_t)h0 * XQ_WSTR + tid * 16;
            int8_t* ldst = &Bs[(tid >> 2) * BPITCH + (tid & 3) * 16];
            i32x4 hv[6];
#pragma unroll
            for (int r6 = 0; r6 < 6; ++r6)
                hv[r6] = *(const i32x4*)(bbase + r6 * XQ_WSTR);
#pragma unroll
            for (int r6 = 0; r6 < 6; ++r6)
                *(i32x4*)(ldst + r6 * BS_ROWB) = hv[r6];
        }
        __syncthreads();   // Bs visible; DMA(s0) long since drained
        issueA(s0 + 1);    // in flight across tap-0 body

        // initial fragments for tap 0
        const int8_t* Acur = &As[(s0 & 1) * 8192];
#pragma unroll
        for (int mt = 0; mt < 8; ++mt)
            af[mt] = *(const i32x4*)(Acur + mt * 1024 + rowA);
#pragma unroll
        for (int nt = 0; nt < 4; ++nt)
            bc[nt] = *(const i32x4*)(&Bs[addrB[nt]]);

#pragma unroll
        for (int tap = 0; tap < 9; ++tap) {
            const int s = s0 + tap;
            if (tap < 8) {
                __syncthreads();                    // DMA(s+1) complete in As[(s+1)&1]
                if (s + 2 < 36) issueA(s + 2);      // overwrites As[s&1]; its reads are closed
                // prefetch B(tap+1) — Bs is stable within this cc
                const int off2 = ((tap + 1) / 3) * BS_ROWB + ((tap + 1) % 3) * BPITCH;
#pragma unroll
                for (int nt = 0; nt < 4; ++nt)
                    bn[nt] = *(const i32x4*)(&Bs[addrB[nt] + off2]);
                const int8_t* Anext = &As[((s + 1) & 1) * 8192];
#pragma unroll
                for (int mt = 0; mt < 8; ++mt) {
                    i32x4 a = af[mt];
#pragma unroll
                    for (int nt = 0; nt < 4; ++nt)
                        acc[mt][nt] = __builtin_amdgcn_mfma_i32_16x16x64_i8(
                            a, bc[nt], acc[mt][nt], 0, 0, 0);
                    af[mt] = *(const i32x4*)(Anext + mt * 1024 + rowA);  // tap+1, hidden
                }
#pragma unroll
                for (int nt = 0; nt < 4; ++nt) bc[nt] = bn[nt];
            } else {
#pragma unroll
                for (int mt = 0; mt < 8; ++mt)
#pragma unroll
                    for (int nt = 0; nt < 4; ++nt)
                        acc[mt][nt] = __builtin_amdgcn_mfma_i32_16x16x64_i8(
                            af[mt], bc[nt], acc[mt][nt], 0, 0, 0);
            }
        }
    }

    // ---- epilogue: o = oblk*128 + mt*16 + quad*4 + r; pix = (h0+pr, pc) ----
    const float am  = __uint_as_float(*amax_bits);
    const float inv = am * (1.0f / 127.0f);
#pragma unroll
    for (int nt = 0; nt < 4; ++nt) {
        if (!live[nt]) continue;
        float* obase = out + ((size_t)n * O_OUT + oblk * 128) * HW
                           + (h0 + pr[nt]) * W_IN + pc[nt];
#pragma unroll
        for (int mt = 0; mt < 8; ++mt) {
#pragma unroll
            for (int r = 0; r < 4; ++r) {
                int ol = mt * 16 + quad * 4 + r;
                float sb = (bias[oblk * 128 + ol] >= 0.0f) ? 1.0f : -1.0f;
                obase[(size_t)ol * HW] = (float)acc[mt][nt][r] * inv + sb;
            }
        }
    }
}

// ================= fallback (only if ws too small): fp32->bf16 direct =================
#define CHW (C_IN * HW)
#define FPITCH 40

__launch_bounds__(256, 2)
__global__ void bconv_fallback(const float* __restrict__ x,
                               const float* __restrict__ w,
                               const float* __restrict__ bias,
                               float* __restrict__ out) {
    __shared__ __attribute__((aligned(16))) __bf16 Asf[128 * FPITCH];
    __shared__ __attribute__((aligned(16))) __bf16 Bsf[128 * FPITCH];

    const int tid  = threadIdx.x;
    const int lane = tid & 63;
    const int wv   = tid >> 6;
    const int pblk = blockIdx.x;
    const int oblk = blockIdx.y;

    const int p_local = tid & 127;
    const int cgrp    = tid >> 7;
    const int pixel   = pblk * 128 + p_local;
    const int n_img   = pixel / HW;
    const int hw      = pixel - n_img * HW;
    const int h       = hw / W_IN;
    const int wx      = hw - h * W_IN;
    const float* xbase = x + (size_t)n_img * CHW;

    f32x4 acc[8][2];
#pragma unroll
    for (int mt = 0; mt < 8; ++mt)
#pragma unroll
        for (int nt = 0; nt < 2; ++nt)
            acc[mt][nt] = (f32x4){0.f, 0.f, 0.f, 0.f};

    const int pix_wave = wv * 32;
    const int row  = lane & 15;
    const int quad = lane >> 4;

    for (int tap = 0; tap < 9; ++tap) {
        const int dh = tap / 3 - 1;
        const int dw = tap % 3 - 1;
        const int hh = h + dh;
        const int ww = wx + dw;
        const bool valid = ((unsigned)hh < (unsigned)H_IN) && ((unsigned)ww < (unsigned)W_IN);
        const int offs = hh * W_IN + ww;

        for (int ck = 0; ck < 8; ++ck) {
            __syncthreads();
#pragma unroll
            for (int rep = 0; rep < 2; ++rep) {
                int v  = tid + rep * 256;
                int oa = v >> 2;
                int c8 = v & 3;
                const float* wsrc = w + (size_t)(oblk * 128 + oa) * K_RAW
                                      + (ck * 32 + c8 * 8) * 9 + tap;
                bf16x8 val;
#pragma unroll
                for (int j = 0; j < 8; ++j)
                    val[j] = (wsrc[j * 9] >= 0.0f) ? (__bf16)1.0f : (__bf16)(-1.0f);
                *(bf16x8*)(&Asf[oa * FPITCH + c8 * 8]) = val;
            }
            {
                const int cbase = (ck * 32 + cgrp * 16) * HW + offs;
#pragma unroll
                for (int g = 0; g < 2; ++g) {
                    bf16x8 vb;
#pragma unroll
                    for (int j = 0; j < 8; ++j) {
                        float f = valid ? xbase[cbase + (g * 8 + j) * HW] : 0.0f;
                        vb[j] = (__bf16)f;
                    }
                    *(bf16x8*)(&Bsf[p_local * FPITCH + cgrp * 16 + g * 8]) = vb;
                }
            }
            __syncthreads();
            bf16x8 bfrag[2];
#pragma unroll
            for (int nt = 0; nt < 2; ++nt)
                bfrag[nt] = *(const bf16x8*)(&Bsf[(pix_wave + nt * 16 + row) * FPITCH + quad * 8]);
#pragma unroll
            for (int mt = 0; mt < 8; ++mt) {
                bf16x8 afrag = *(const bf16x8*)(&Asf[(mt * 16 + row) * FPITCH + quad * 8]);
#pragma unroll
                for (int nt = 0; nt < 2; ++nt)
                    acc[mt][nt] = __builtin_amdgcn_mfma_f32_16x16x32_bf16(
                        afrag, bfrag[nt], acc[mt][nt], 0, 0, 0);
            }
        }
    }

#pragma unroll
    for (int nt = 0; nt < 2; ++nt) {
        int pix = pblk * 128 + pix_wave + nt * 16 + row;
        int ni  = pix / HW;
        int phw = pix - ni * HW;
        float* obase = out + (size_t)ni * (O_OUT * HW) + phw;
#pragma unroll
        for (int mt = 0; mt < 8; ++mt) {
            int o0 = oblk * 128 + mt * 16 + quad * 4;
#pragma unroll
            for (int r = 0; r < 4; ++r) {
                int o = o0 + r;
                float sb = (bias[o] >= 0.0f) ? 1.0f : -1.0f;
                obase[(size_t)o * HW] = acc[mt][nt][r] + sb;
            }
        }
    }
}

extern "C" void kernel_launch(void* const* d_in, const int* in_sizes, int n_in,
                              void* d_out, int out_size, void* d_ws, size_t ws_size,
                              hipStream_t stream) {
    const float* x    = (const float*)d_in[0];
    const float* w    = (const float*)d_in[1];
    const float* bias = (const float*)d_in[2];
    float* out        = (float*)d_out;

    if (ws_size >= WS_NEED) {
        int8_t*   xq = (int8_t*)d_ws;
        int8_t*   wq = (int8_t*)d_ws + XQ_BYTES;
        unsigned* am = (unsigned*)((char*)d_ws + AM_OFF);

        amax_zero<<<1, 64, 0, stream>>>(am);
        amax_kernel<<<1024, 256, 0, stream>>>(x, am);
        xtrans_q<<<dim3(58, 4, N_IMG), dim3(256), 0, stream>>>(x, xq, am);
        wshuf_q<<<144, 256, 0, stream>>>(w, wq);
        bconv_i8<<<dim3(N_IMG * 14, 2), dim3(256), 0, stream>>>(xq, wq, bias, am, out);
    } else {
        bconv_fallback<<<dim3((N_IMG * HW) / 128, 2), dim3(256), 0, stream>>>(
            x, w, bias, out);
    }
}